// Round 1
// baseline (85.830 us; speedup 1.0000x reference)
//
#include <hip/hip_runtime.h>

#define BDIM 128
#define TDIM 512
#define DDIM 64
#define HDIM 256

typedef short s16x8 __attribute__((ext_vector_type(8)));
typedef float f32x4 __attribute__((ext_vector_type(4)));

__device__ __forceinline__ short f2bf(float f) {
  __bf16 b = (__bf16)f;
  return __builtin_bit_cast(short, b);
}

__device__ __forceinline__ s16x8 pack_bf8(float4 lo, float4 hi) {
  s16x8 v;
  v[0] = f2bf(lo.x); v[1] = f2bf(lo.y); v[2] = f2bf(lo.z); v[3] = f2bf(lo.w);
  v[4] = f2bf(hi.x); v[5] = f2bf(hi.y); v[6] = f2bf(hi.z); v[7] = f2bf(hi.w);
  return v;
}

__device__ __forceinline__ float sigm(float x) { return 1.0f / (1.0f + __expf(-x)); }
__device__ __forceinline__ float tanh_fast(float x) { return 1.0f - 2.0f / (__expf(2.0f * x) + 1.0f); }

// Grid: (128, 4) blocks, 256 threads (4 waves). Block = (b, h-chunk of 64).
// Wave w owns h columns [hc*64 + w*16, +16). Computes s0h,s1h,s0c,s1c into sbuf.
__global__ __launch_bounds__(256) void fused_lstm(
    const float* __restrict__ x, const float* __restrict__ h0,
    const float* __restrict__ c0, const float* __restrict__ Wih,
    const float* __restrict__ Whh, const float* __restrict__ bih,
    const float* __restrict__ bhh, const int* __restrict__ longp,
    float* __restrict__ sbuf)
{
  const int b    = blockIdx.x;
  const int hc   = blockIdx.y;          // 0..3
  const int tid  = threadIdx.x;
  const int wave = tid >> 6;            // 0..3
  const int lane = tid & 63;
  const int col  = lane & 15;           // n-col within 16-slice (also A-row t offset)
  const int kg   = lane >> 4;           // 0..3 k-group
  const int h    = hc * 64 + wave * 16 + col;   // global h index

  __shared__ float hs[HDIM];
  __shared__ float w0s[TDIM];
  __shared__ float w1s[TDIM];
  __shared__ float hh_s[256];           // [g*64 + h_local]

  const float* xb = x + (size_t)b * (TDIM * DDIM);
  const float inv_long = 1.0f / (float)(*longp);

  if (tid < HDIM) hs[tid] = h0[b * HDIM + tid];
  for (int t = tid; t < TDIM; t += 256) {
    w0s[t] = xb[t * DDIM + 0] * inv_long;
    w1s[t] = xb[t * DDIM + 1];
  }
  __syncthreads();

  // hh term: col = g*256 + hc*64 + hl  (one column per thread, fp32)
  {
    const int g  = tid >> 6;
    const int hl = tid & 63;
    const int colw = g * HDIM + hc * 64 + hl;
    const float4* wr = (const float4*)(Whh + (size_t)colw * HDIM);
    const float4* hv = (const float4*)hs;
    float acc = 0.f;
    #pragma unroll 8
    for (int k = 0; k < HDIM / 4; ++k) {
      float4 w = wr[k], hh4 = hv[k];
      acc += w.x * hh4.x + w.y * hh4.y + w.z * hh4.z + w.w * hh4.w;
    }
    hh_s[tid] = acc + bih[colw] + bhh[colw];
  }
  __syncthreads();

  float hhv[4];
  #pragma unroll
  for (int g = 0; g < 4; ++g) hhv[g] = hh_s[g * 64 + wave * 16 + col];
  const float cprev = c0[b * HDIM + h];

  // W_ih fragments: B[k][n] = W_ih[n][k]; lane supplies n=col(global h per gate),
  // k = kg*8 + j (+32 per k-step). Row-major W_ih makes this a contiguous 8-float read.
  s16x8 wf[4][2];
  #pragma unroll
  for (int g = 0; g < 4; ++g) {
    const float4* wrow = (const float4*)(Wih + (size_t)(g * HDIM + h) * DDIM);
    #pragma unroll
    for (int ks = 0; ks < 2; ++ks)
      wf[g][ks] = pack_bf8(wrow[kg * 2 + ks * 8], wrow[kg * 2 + ks * 8 + 1]);
  }

  float s0h = 0.f, s1h = 0.f, s0c = 0.f, s1c = 0.f;

  // A fragment source: row = tb + (lane&15), k = kg*8 + j (+32)
  const float* arow = xb + (size_t)col * DDIM + kg * 8;

  float4 cur0 = *(const float4*)(arow + 0);
  float4 cur1 = *(const float4*)(arow + 4);
  float4 cur2 = *(const float4*)(arow + 32);
  float4 cur3 = *(const float4*)(arow + 36);
  float4 nxt0 = cur0, nxt1 = cur1, nxt2 = cur2, nxt3 = cur3;

  for (int tb = 0; tb < TDIM; tb += 16) {
    if (tb + 16 < TDIM) {
      const float* p = arow + (size_t)(tb + 16) * DDIM;
      nxt0 = *(const float4*)(p + 0);
      nxt1 = *(const float4*)(p + 4);
      nxt2 = *(const float4*)(p + 32);
      nxt3 = *(const float4*)(p + 36);
    }
    s16x8 a0 = pack_bf8(cur0, cur1);
    s16x8 a1 = pack_bf8(cur2, cur3);

    f32x4 acc[4];
    #pragma unroll
    for (int g = 0; g < 4; ++g) {
      f32x4 z = {0.f, 0.f, 0.f, 0.f};
      z = __builtin_amdgcn_mfma_f32_16x16x32_bf16(a0, wf[g][0], z, 0, 0, 0);
      z = __builtin_amdgcn_mfma_f32_16x16x32_bf16(a1, wf[g][1], z, 0, 0, 0);
      acc[g] = z;
    }

    #pragma unroll
    for (int r = 0; r < 4; ++r) {
      const int tt = tb + kg * 4 + r;   // C/D: row = (lane>>4)*4 + r, col = lane&15
      float ig = sigm(acc[0][r] + hhv[0]);
      float fg = sigm(acc[1][r] + hhv[1]);
      float gg = tanh_fast(acc[2][r] + hhv[2]);
      float og = sigm(acc[3][r] + hhv[3]);
      float cc = fg * cprev + ig * gg;
      float hv = og * tanh_fast(cc);
      if (tt > 0) {                     // t=0 row is masked out of h_all/c_all
        float a0w = w0s[tt], a1w = w1s[tt];
        s0h += hv * a0w; s1h += hv * a1w;
        s0c += cc * a0w; s1c += cc * a1w;
      }
    }
    cur0 = nxt0; cur1 = nxt1; cur2 = nxt2; cur3 = nxt3;
  }

  // reduce over the 4 k-groups (lanes sharing col): xor 16, 32
  s0h += __shfl_xor(s0h, 16, 64); s0h += __shfl_xor(s0h, 32, 64);
  s1h += __shfl_xor(s1h, 16, 64); s1h += __shfl_xor(s1h, 32, 64);
  s0c += __shfl_xor(s0c, 16, 64); s0c += __shfl_xor(s0c, 32, 64);
  s1c += __shfl_xor(s1c, 16, 64); s1c += __shfl_xor(s1c, 32, 64);

  if (kg == 0) {
    sbuf[0 * (BDIM * HDIM) + b * HDIM + h] = s0h;
    sbuf[1 * (BDIM * HDIM) + b * HDIM + h] = s1h;
    sbuf[2 * (BDIM * HDIM) + b * HDIM + h] = s0c;
    sbuf[3 * (BDIM * HDIM) + b * HDIM + h] = s1c;
  }
}

// Grid: 128 blocks (b), 256 threads. Epilogue GEMV + bias*Wsum terms.
__global__ __launch_bounds__(256) void out_kernel(
    const float* __restrict__ x, const float* __restrict__ f1w,
    const float* __restrict__ f1b, const float* __restrict__ f2w,
    const float* __restrict__ f2b, const int* __restrict__ longp,
    const float* __restrict__ sbuf, float* __restrict__ out)
{
  const int b = blockIdx.x, tid = threadIdx.x;
  __shared__ float s0h[256], s1h[256], s0c[256], s1c[256];
  __shared__ float wsum[8];
  const float* xb = x + (size_t)b * (TDIM * DDIM);

  s0h[tid] = sbuf[0 * (BDIM * HDIM) + b * HDIM + tid];
  s1h[tid] = sbuf[1 * (BDIM * HDIM) + b * HDIM + tid];
  s0c[tid] = sbuf[2 * (BDIM * HDIM) + b * HDIM + tid];
  s1c[tid] = sbuf[3 * (BDIM * HDIM) + b * HDIM + tid];

  float w0p = 0.f, w1p = 0.f;
  for (int t = tid; t < TDIM; t += 256) {
    w0p += xb[t * DDIM];
    w1p += xb[t * DDIM + 1];
  }
  #pragma unroll
  for (int off = 1; off < 64; off <<= 1) {
    w0p += __shfl_xor(w0p, off, 64);
    w1p += __shfl_xor(w1p, off, 64);
  }
  if ((tid & 63) == 0) { wsum[tid >> 6] = w0p; wsum[4 + (tid >> 6)] = w1p; }
  __syncthreads();

  const float inv_long = 1.0f / (float)(*longp);
  const float W0 = (wsum[0] + wsum[1] + wsum[2] + wsum[3]) * inv_long; // includes t=0
  const float W1 = (wsum[4] + wsum[5] + wsum[6] + wsum[7]);

  float rh, rc;
  if (tid < 128) {                       // "first": f1_w with w0-weighted sums
    const float4* wr = (const float4*)(f1w + (size_t)tid * HDIM);
    float ah = 0.f, ac = 0.f;
    #pragma unroll 8
    for (int k = 0; k < HDIM / 4; ++k) {
      float4 w = wr[k];
      ah += w.x * s0h[4*k] + w.y * s0h[4*k+1] + w.z * s0h[4*k+2] + w.w * s0h[4*k+3];
      ac += w.x * s0c[4*k] + w.y * s0c[4*k+1] + w.z * s0c[4*k+2] + w.w * s0c[4*k+3];
    }
    const float bb = f1b[tid];
    rh = ah + bb * W0;
    rc = ac + bb * W0;
  } else {                               // "second": f2_w with w1-weighted sums
    const int k0 = tid - 128;
    const float4* wr = (const float4*)(f2w + (size_t)k0 * HDIM);
    float ah = 0.f, ac = 0.f;
    #pragma unroll 8
    for (int k = 0; k < HDIM / 4; ++k) {
      float4 w = wr[k];
      ah += w.x * s1h[4*k] + w.y * s1h[4*k+1] + w.z * s1h[4*k+2] + w.w * s1h[4*k+3];
      ac += w.x * s1c[4*k] + w.y * s1c[4*k+1] + w.z * s1c[4*k+2] + w.w * s1c[4*k+3];
    }
    const float bb = f2b[k0];
    rh = ah + bb * W1;
    rc = ac + bb * W1;
  }
  out[b * HDIM + tid] = rh;                      // agg(h_all) -> (1,B,256)
  out[BDIM * HDIM + b * HDIM + tid] = rc;        // agg(c_all)
}

extern "C" void kernel_launch(void* const* d_in, const int* in_sizes, int n_in,
                              void* d_out, int out_size, void* d_ws, size_t ws_size,
                              hipStream_t stream) {
  const float* x   = (const float*)d_in[0];
  const float* h0  = (const float*)d_in[1];
  const float* c0  = (const float*)d_in[2];
  const float* Wih = (const float*)d_in[3];
  const float* Whh = (const float*)d_in[4];
  const float* bih = (const float*)d_in[5];
  const float* bhh = (const float*)d_in[6];
  const float* f1w = (const float*)d_in[7];
  const float* f1b = (const float*)d_in[8];
  const float* f2w = (const float*)d_in[9];
  const float* f2b = (const float*)d_in[10];
  const int*  longp = (const int*)d_in[11];
  float* out  = (float*)d_out;
  float* sbuf = (float*)d_ws;   // 4 * B * H floats = 512 KB

  dim3 g1(BDIM, 4);
  fused_lstm<<<g1, 256, 0, stream>>>(x, h0, c0, Wih, Whh, bih, bhh, longp, sbuf);
  out_kernel<<<BDIM, 256, 0, stream>>>(x, f1w, f1b, f2w, f2b, longp, sbuf, out);
}